// Round 10
// baseline (958.597 us; speedup 1.0000x reference)
//
#include <hip/hip_runtime.h>
#include <hip/hip_bf16.h>

#define HID 64
#define FSH 9                  // nodes per fill bucket = 512
#define FB 196                 // buckets: 196*512 = 100352 >= N
#define FCAP 17408             // per-bucket staging capacity (mean 16384, +8 sigma)
#define FCH 16384              // edges per phase-A block

// ---------------- zero int buffer ----------------
__global__ void zero_kernel(int* __restrict__ p, int n) {
    int i = blockIdx.x * blockDim.x + threadIdx.x;
    if (i < n) p[i] = 0;
}

// ---------------- fill phase A: bin edges into FB dst-buckets (compact staging) ----------------
__global__ __launch_bounds__(256) void fillA_kernel(const int* __restrict__ src,
                                                    const int* __restrict__ dst,
                                                    int* __restrict__ gcur,
                                                    int* __restrict__ srcA,
                                                    unsigned short* __restrict__ locA,
                                                    int E) {
    __shared__ int hist[FB];
    __shared__ int cur[FB];
    int t = threadIdx.x;
    int base = blockIdx.x * FCH;
    int lim = E - base;
    if (lim > FCH) lim = FCH;
    if (lim <= 0) return;
    for (int i = t; i < FB; i += 256) hist[i] = 0;
    __syncthreads();
    for (int i = t; i < lim; i += 256) atomicAdd(&hist[dst[base + i] >> FSH], 1);
    __syncthreads();
    for (int i = t; i < FB; i += 256) cur[i] = atomicAdd(&gcur[i], hist[i]);
    __syncthreads();
    for (int i = t; i < lim; i += 256) {
        int d = dst[base + i];
        int s = src[base + i];
        int bkt = d >> FSH;
        int idx = atomicAdd(&cur[bkt], 1);
        if (idx < FCAP) {
            srcA[(size_t)bkt * FCAP + idx] = s;
            locA[(size_t)bkt * FCAP + idx] = (unsigned short)(d & ((1 << FSH) - 1));
        }
    }
}

// ---------------- exclusive scan of FB bucket counts -> bbase ----------------
__global__ __launch_bounds__(256) void bucketscan_kernel(const int* __restrict__ gcur,
                                                         int* __restrict__ bbase, int nb) {
    __shared__ int buf[256];
    int tid = threadIdx.x;
    int v = (tid < nb) ? gcur[tid] : 0;
    buf[tid] = v;
    __syncthreads();
#pragma unroll
    for (int o = 1; o < 256; o <<= 1) {
        int t = (tid >= o) ? buf[tid - o] : 0;
        __syncthreads();
        buf[tid] += t;
        __syncthreads();
    }
    if (tid < nb) bbase[tid] = buf[tid] - v;  // exclusive
}

// ---------------- fill phase B: per-bucket hist + scan + rowptr/dinv + fine fill ----------------
__global__ __launch_bounds__(256) void fillB_kernel(const int* __restrict__ gcur,
                                                    const int* __restrict__ bbase,
                                                    const int* __restrict__ srcA,
                                                    const unsigned short* __restrict__ locA,
                                                    int* __restrict__ rowptr,
                                                    float* __restrict__ dinv,
                                                    int* __restrict__ col, int N) {
    __shared__ int hist[1 << FSH];   // local degree -> later cursor
    __shared__ int buf[256];
    int b = blockIdx.x;
    int t = threadIdx.x;
    int n0 = b << FSH;
    for (int i = t; i < (1 << FSH); i += 256) hist[i] = 0;
    __syncthreads();
    int cnt = gcur[b];
    if (cnt > FCAP) cnt = FCAP;
    const int* sA = srcA + (size_t)b * FCAP;
    const unsigned short* lA = locA + (size_t)b * FCAP;
    for (int r = t; r < cnt; r += 256) atomicAdd(&hist[lA[r]], 1);
    __syncthreads();
    // scan 512 local degrees (2 per thread)
    int a0 = hist[2 * t], a1 = hist[2 * t + 1];
    int pair = a0 + a1;
    buf[t] = pair;
    __syncthreads();
#pragma unroll
    for (int o = 1; o < 256; o <<= 1) {
        int tv = (t >= o) ? buf[t - o] : 0;
        __syncthreads();
        buf[t] += tv;
        __syncthreads();
    }
    int excl = buf[t] - pair + bbase[b];  // exclusive over pairs + bucket base
    int n_a = n0 + 2 * t, n_b = n0 + 2 * t + 1;
    if (n_a <= N) rowptr[n_a] = excl;
    if (n_b <= N) rowptr[n_b] = excl + a0;
    if (n_a < N) dinv[n_a] = 1.0f / sqrtf((float)(a0 + 1));
    if (n_b < N) dinv[n_b] = 1.0f / sqrtf((float)(a1 + 1));
    __syncthreads();
    hist[2 * t] = excl;            // reuse hist as cursors
    hist[2 * t + 1] = excl + a0;
    __syncthreads();
    for (int r = t; r < cnt; r += 256) {
        int s = sA[r];
        int pos = atomicAdd(&hist[lA[r]], 1);
        col[pos] = s;
    }
}

// ---------------- dense linear + dinv scale: out[n,:] = dinv[n] * (x[n,:] @ W) ----------------
template <int K>
__global__ __launch_bounds__(256) void linscale_kernel(const float* __restrict__ x,
                                                       const float* __restrict__ W,
                                                       const float* __restrict__ dinv,
                                                       float* __restrict__ out, int N) {
    __shared__ float4 Wl[K * 16];
    const float4* W4 = reinterpret_cast<const float4*>(W);
    for (int i = threadIdx.x; i < K * 16; i += blockDim.x) Wl[i] = W4[i];
    __syncthreads();
    int node = blockIdx.x * blockDim.x + threadIdx.x;
    if (node >= N) return;
    float4 acc[16];
#pragma unroll
    for (int c = 0; c < 16; ++c) acc[c] = make_float4(0.f, 0.f, 0.f, 0.f);
    const float* xr = x + (size_t)node * K;
    for (int k = 0; k < K; ++k) {
        float xv = xr[k];
#pragma unroll
        for (int c = 0; c < 16; ++c) {
            float4 w = Wl[k * 16 + c];
            acc[c].x += xv * w.x;
            acc[c].y += xv * w.y;
            acc[c].z += xv * w.z;
            acc[c].w += xv * w.w;
        }
    }
    float dv = dinv[node];
    float4* o = reinterpret_cast<float4*>(out + (size_t)node * HID);
#pragma unroll
    for (int c = 0; c < 16; ++c) {
        float4 a = acc[c];
        a.x *= dv; a.y *= dv; a.z *= dv; a.w *= dv;
        o[c] = a;
    }
}

// ---------------- fused gather + relu(+b) + nextW + dinv-prescale ----------------
// h[d][lane]   = relu(dinv[d]*(hs[d,:]+sum hs[col,:]) + b[lane])
// out[d][lane] = dinv[d] * sum_k h[d][k] * W[k][lane]
__global__ __launch_bounds__(256) void gatherlin_kernel(const int* __restrict__ rowptr,
                                                        const int* __restrict__ col,
                                                        const float* __restrict__ dinv,
                                                        const float* __restrict__ hs,
                                                        const float* __restrict__ b,
                                                        const float* __restrict__ W,
                                                        float* __restrict__ out, int N) {
    __shared__ float Wl[64 * 64];
    for (int i = threadIdx.x; i < 64 * 64; i += blockDim.x) Wl[i] = W[i];
    __syncthreads();
    int lane = threadIdx.x & 63;
    int wid = (blockIdx.x * blockDim.x + threadIdx.x) >> 6;
    int nw = (gridDim.x * blockDim.x) >> 6;
    float bias = b[lane];
    for (int d = wid; d < N; d += nw) {
        int beg = rowptr[d], end = rowptr[d + 1];
        float acc = hs[((size_t)d << 6) + lane];  // self-loop (pre-scaled by dinv[d])
        for (int ebase = beg; ebase < end; ebase += 64) {
            int e = ebase + lane;
            int cv = (e < end) ? col[e] : 0;
            int cnt = end - ebase;
            if (cnt > 64) cnt = 64;
            int k = 0;
            for (; k + 4 <= cnt; k += 4) {
                int s0 = __shfl(cv, k + 0);
                int s1 = __shfl(cv, k + 1);
                int s2 = __shfl(cv, k + 2);
                int s3 = __shfl(cv, k + 3);
                float v0 = hs[((size_t)s0 << 6) + lane];
                float v1 = hs[((size_t)s1 << 6) + lane];
                float v2 = hs[((size_t)s2 << 6) + lane];
                float v3 = hs[((size_t)s3 << 6) + lane];
                acc += (v0 + v1) + (v2 + v3);
            }
            for (; k < cnt; ++k) acc += hs[((size_t)__shfl(cv, k) << 6) + lane];
        }
        float dv = dinv[d];
        float h = fmaxf(fmaf(acc, dv, bias), 0.f);
        float o = 0.f;
#pragma unroll
        for (int k = 0; k < 64; ++k) o = fmaf(__shfl(h, k), Wl[k * 64 + lane], o);
        out[((size_t)d << 6) + lane] = o * dv;
    }
}

// ---------------- fused gather + relu(+b) + MLP head ----------------
// h = relu(dinv*(agg)+b3); out[d] = relu(h@Wh1+bh1)@Wh2 + bh2
__global__ __launch_bounds__(256) void gatherhead_kernel(const int* __restrict__ rowptr,
                                                         const int* __restrict__ col,
                                                         const float* __restrict__ dinv,
                                                         const float* __restrict__ hs,
                                                         const float* __restrict__ b,
                                                         const float* __restrict__ Wh1,
                                                         const float* __restrict__ bh1,
                                                         const float* __restrict__ Wh2,
                                                         const float* __restrict__ bh2,
                                                         float* __restrict__ out, int N) {
    __shared__ float Wl[64 * 64];
    for (int i = threadIdx.x; i < 64 * 64; i += blockDim.x) Wl[i] = Wh1[i];
    __syncthreads();
    int lane = threadIdx.x & 63;
    int wid = (blockIdx.x * blockDim.x + threadIdx.x) >> 6;
    int nw = (gridDim.x * blockDim.x) >> 6;
    float bias = b[lane];
    float bh = bh1[lane];
    float w2 = Wh2[lane];
    float b2 = bh2[0];
    for (int d = wid; d < N; d += nw) {
        int beg = rowptr[d], end = rowptr[d + 1];
        float acc = hs[((size_t)d << 6) + lane];
        for (int ebase = beg; ebase < end; ebase += 64) {
            int e = ebase + lane;
            int cv = (e < end) ? col[e] : 0;
            int cnt = end - ebase;
            if (cnt > 64) cnt = 64;
            int k = 0;
            for (; k + 4 <= cnt; k += 4) {
                int s0 = __shfl(cv, k + 0);
                int s1 = __shfl(cv, k + 1);
                int s2 = __shfl(cv, k + 2);
                int s3 = __shfl(cv, k + 3);
                float v0 = hs[((size_t)s0 << 6) + lane];
                float v1 = hs[((size_t)s1 << 6) + lane];
                float v2 = hs[((size_t)s2 << 6) + lane];
                float v3 = hs[((size_t)s3 << 6) + lane];
                acc += (v0 + v1) + (v2 + v3);
            }
            for (; k < cnt; ++k) acc += hs[((size_t)__shfl(cv, k) << 6) + lane];
        }
        float h = fmaxf(fmaf(acc, dinv[d], bias), 0.f);
        float o = bh;
#pragma unroll
        for (int k = 0; k < 64; ++k) o = fmaf(__shfl(h, k), Wl[k * 64 + lane], o);
        o = fmaxf(o, 0.f) * w2;
#pragma unroll
        for (int off = 32; off > 0; off >>= 1) o += __shfl_down(o, off);
        if (lane == 0) out[d] = o + b2;
    }
}

extern "C" void kernel_launch(void* const* d_in, const int* in_sizes, int n_in,
                              void* d_out, int out_size, void* d_ws, size_t ws_size,
                              hipStream_t stream) {
    const float* x = (const float*)d_in[0];
    const int* edge = (const int*)d_in[1];   // harness passes integer inputs as int32
    const float* W1 = (const float*)d_in[2];
    const float* b1 = (const float*)d_in[3];
    const float* W2 = (const float*)d_in[4];
    const float* b2 = (const float*)d_in[5];
    const float* W3 = (const float*)d_in[6];
    const float* b3 = (const float*)d_in[7];
    const float* Wh1 = (const float*)d_in[8];
    const float* bh1 = (const float*)d_in[9];
    const float* Wh2 = (const float*)d_in[10];
    const float* bh2 = (const float*)d_in[11];

    int N = in_sizes[0] / 61;   // 100000
    int E = in_sizes[1] / 2;    // 3200000
    const int* srcs = edge;
    const int* dsts = edge + E;
    float* out = (float*)d_out;

    // workspace: dinv(N) | rowptr(N+1) | gcur(FB) | bbase(FB) | col(E) | A(N*64) | B(N*64)
    // fill staging aliases B (dead until linscale 1)
    char* ws = (char*)d_ws;
    size_t off = 0;
    auto alloc = [&](size_t bytes) {
        void* p = ws + off;
        off += (bytes + 255) & ~(size_t)255;
        return p;
    };
    float* dinv = (float*)alloc((size_t)N * 4);
    int* rowptr = (int*)alloc((size_t)(N + 1) * 4);
    int* gcur = (int*)alloc((size_t)FB * 4);
    int* bbase = (int*)alloc((size_t)FB * 4);
    int* col = (int*)alloc((size_t)E * 4);
    float* A = (float*)alloc((size_t)N * HID * 4);
    float* B = (float*)alloc((size_t)N * HID * 4);
    if (off > ws_size) return;  // fail cleanly (absmax), not a fault
    int* srcA = (int*)B;        // alias: staging dead after fillB
    unsigned short* locA = (unsigned short*)((char*)B + (size_t)FB * FCAP * 4);
    // staging total = FB*FCAP*6 = ~20.5 MB <= 25.6 MB (B)

    int gN = (N + 255) / 256;
    int gA = (E + FCH - 1) / FCH;

    // ---- CSR build (once, reused by all 3 layers) ----
    zero_kernel<<<1, 256, 0, stream>>>(gcur, FB);
    fillA_kernel<<<gA, 256, 0, stream>>>(srcs, dsts, gcur, srcA, locA, E);
    bucketscan_kernel<<<1, 256, 0, stream>>>(gcur, bbase, FB);
    fillB_kernel<<<FB, 256, 0, stream>>>(gcur, bbase, srcA, locA, rowptr, dinv, col, N);

    // ---- layer 1 dense: B = dinv * (x @ W1) ----
    linscale_kernel<61><<<gN, 256, 0, stream>>>(x, W1, dinv, B, N);
    // ---- layer 1 agg fused with layer 2 dense: A = dinv * (relu(agg(B)+b1) @ W2) ----
    gatherlin_kernel<<<4096, 256, 0, stream>>>(rowptr, col, dinv, B, b1, W2, A, N);
    // ---- layer 2 agg fused with layer 3 dense: B = dinv * (relu(agg(A)+b2) @ W3) ----
    gatherlin_kernel<<<4096, 256, 0, stream>>>(rowptr, col, dinv, A, b2, W3, B, N);
    // ---- layer 3 agg fused with MLP head ----
    gatherhead_kernel<<<4096, 256, 0, stream>>>(rowptr, col, dinv, B, b3,
                                                Wh1, bh1, Wh2, bh2, out, N);
}

// Round 11
// 538.356 us; speedup vs baseline: 1.7806x; 1.7806x over previous
//
#include <hip/hip_runtime.h>
#include <hip/hip_fp16.h>

#define HID 64
#define FSH 9                  // nodes per fill bucket = 512
#define FB 196                 // buckets: 196*512 = 100352 >= N
#define FCAP 17408             // per-bucket staging capacity (mean 16326, +8 sigma)
#define FCH 8192               // edges per phase-A block (391 blocks -> ~1.5/CU)

// ---------------- zero int buffer ----------------
__global__ void zero_kernel(int* __restrict__ p, int n) {
    int i = blockIdx.x * blockDim.x + threadIdx.x;
    if (i < n) p[i] = 0;
}

// ---------------- fill phase A: bin edges into FB dst-buckets (compact staging) ----------------
__global__ __launch_bounds__(256) void fillA_kernel(const int* __restrict__ src,
                                                    const int* __restrict__ dst,
                                                    int* __restrict__ gcur,
                                                    int* __restrict__ srcA,
                                                    unsigned short* __restrict__ locA,
                                                    int E) {
    __shared__ int hist[FB];
    __shared__ int cur[FB];
    int t = threadIdx.x;
    int base = blockIdx.x * FCH;
    int lim = E - base;
    if (lim > FCH) lim = FCH;
    if (lim <= 0) return;
    for (int i = t; i < FB; i += 256) hist[i] = 0;
    __syncthreads();
    for (int i = t; i < lim; i += 256) atomicAdd(&hist[dst[base + i] >> FSH], 1);
    __syncthreads();
    for (int i = t; i < FB; i += 256) cur[i] = atomicAdd(&gcur[i], hist[i]);
    __syncthreads();
    for (int i = t; i < lim; i += 256) {
        int d = dst[base + i];
        int s = src[base + i];
        int bkt = d >> FSH;
        int idx = atomicAdd(&cur[bkt], 1);
        if (idx < FCAP) {
            srcA[(size_t)bkt * FCAP + idx] = s;
            locA[(size_t)bkt * FCAP + idx] = (unsigned short)(d & ((1 << FSH) - 1));
        }
    }
}

// ---------------- exclusive scan of FB bucket counts -> bbase ----------------
__global__ __launch_bounds__(256) void bucketscan_kernel(const int* __restrict__ gcur,
                                                         int* __restrict__ bbase, int nb) {
    __shared__ int buf[256];
    int tid = threadIdx.x;
    int v = (tid < nb) ? gcur[tid] : 0;
    buf[tid] = v;
    __syncthreads();
#pragma unroll
    for (int o = 1; o < 256; o <<= 1) {
        int t = (tid >= o) ? buf[tid - o] : 0;
        __syncthreads();
        buf[tid] += t;
        __syncthreads();
    }
    if (tid < nb) bbase[tid] = buf[tid] - v;  // exclusive
}

// ---------------- fill phase B: per-bucket hist + scan + rowptr/dinv + fine fill ----------------
__global__ __launch_bounds__(256) void fillB_kernel(const int* __restrict__ gcur,
                                                    const int* __restrict__ bbase,
                                                    const int* __restrict__ srcA,
                                                    const unsigned short* __restrict__ locA,
                                                    int* __restrict__ rowptr,
                                                    float* __restrict__ dinv,
                                                    int* __restrict__ col, int N) {
    __shared__ int hist[1 << FSH];   // local degree -> later cursor
    __shared__ int buf[256];
    int b = blockIdx.x;
    int t = threadIdx.x;
    int n0 = b << FSH;
    for (int i = t; i < (1 << FSH); i += 256) hist[i] = 0;
    __syncthreads();
    int cnt = gcur[b];
    if (cnt > FCAP) cnt = FCAP;
    const int* sA = srcA + (size_t)b * FCAP;
    const unsigned short* lA = locA + (size_t)b * FCAP;
    for (int r = t; r < cnt; r += 256) atomicAdd(&hist[lA[r]], 1);
    __syncthreads();
    // scan 512 local degrees (2 per thread)
    int a0 = hist[2 * t], a1 = hist[2 * t + 1];
    int pair = a0 + a1;
    buf[t] = pair;
    __syncthreads();
#pragma unroll
    for (int o = 1; o < 256; o <<= 1) {
        int tv = (t >= o) ? buf[t - o] : 0;
        __syncthreads();
        buf[t] += tv;
        __syncthreads();
    }
    int excl = buf[t] - pair + bbase[b];  // exclusive over pairs + bucket base
    int n_a = n0 + 2 * t, n_b = n0 + 2 * t + 1;
    if (n_a <= N) rowptr[n_a] = excl;
    if (n_b <= N) rowptr[n_b] = excl + a0;
    if (n_a < N) dinv[n_a] = 1.0f / sqrtf((float)(a0 + 1));
    if (n_b < N) dinv[n_b] = 1.0f / sqrtf((float)(a1 + 1));
    __syncthreads();
    hist[2 * t] = excl;            // reuse hist as cursors
    hist[2 * t + 1] = excl + a0;
    __syncthreads();
    for (int r = t; r < cnt; r += 256) {
        int s = sA[r];
        int pos = atomicAdd(&hist[lA[r]], 1);
        col[pos] = s;
    }
}

// ---------------- dense linear + dinv scale -> f16 rows: out[n,:] = f16(dinv[n]*(x[n,:]@W)) ----------------
template <int K, typename XT>
__global__ __launch_bounds__(256) void linscale_kernel(const XT* __restrict__ x,
                                                       const float* __restrict__ W,
                                                       const float* __restrict__ dinv,
                                                       __half* __restrict__ out, int N) {
    __shared__ float4 Wl[K * 16];
    const float4* W4 = reinterpret_cast<const float4*>(W);
    for (int i = threadIdx.x; i < K * 16; i += blockDim.x) Wl[i] = W4[i];
    __syncthreads();
    int node = blockIdx.x * blockDim.x + threadIdx.x;
    if (node >= N) return;
    float4 acc[16];
#pragma unroll
    for (int c = 0; c < 16; ++c) acc[c] = make_float4(0.f, 0.f, 0.f, 0.f);
    const XT* xr = x + (size_t)node * K;
    for (int k = 0; k < K; ++k) {
        float xv = (float)xr[k];
#pragma unroll
        for (int c = 0; c < 16; ++c) {
            float4 w = Wl[k * 16 + c];
            acc[c].x += xv * w.x;
            acc[c].y += xv * w.y;
            acc[c].z += xv * w.z;
            acc[c].w += xv * w.w;
        }
    }
    float dv = dinv[node];
    __half2* o = reinterpret_cast<__half2*>(out + (size_t)node * HID);
#pragma unroll
    for (int c = 0; c < 16; ++c) {
        o[c * 2 + 0] = __floats2half2_rn(acc[c].x * dv, acc[c].y * dv);
        o[c * 2 + 1] = __floats2half2_rn(acc[c].z * dv, acc[c].w * dv);
    }
}

// ---------------- gather-aggregate over f16 rows ----------------
// out[d,:] = f16( relu(dinv[d]*(hs[d,:] + sum_e hs[col[e],:]) + b) )
__global__ __launch_bounds__(256) void gather_kernel(const int* __restrict__ rowptr,
                                                     const int* __restrict__ col,
                                                     const float* __restrict__ dinv,
                                                     const __half* __restrict__ hs,
                                                     const float* __restrict__ b,
                                                     __half* __restrict__ out, int N) {
    int lane = threadIdx.x & 63;
    int wid = (blockIdx.x * blockDim.x + threadIdx.x) >> 6;
    int nw = (gridDim.x * blockDim.x) >> 6;
    float bias = b[lane];
    for (int d = wid; d < N; d += nw) {
        int beg = rowptr[d], end = rowptr[d + 1];
        float acc = __half2float(hs[((size_t)d << 6) + lane]);  // self-loop (pre-scaled)
        for (int ebase = beg; ebase < end; ebase += 64) {
            int e = ebase + lane;
            int cv = (e < end) ? col[e] : 0;   // one lane-strided load covers <=64 edges
            int cnt = end - ebase;
            if (cnt > 64) cnt = 64;
            int k = 0;
            for (; k + 4 <= cnt; k += 4) {
                int s0 = __shfl(cv, k + 0);
                int s1 = __shfl(cv, k + 1);
                int s2 = __shfl(cv, k + 2);
                int s3 = __shfl(cv, k + 3);
                float v0 = __half2float(hs[((size_t)s0 << 6) + lane]);
                float v1 = __half2float(hs[((size_t)s1 << 6) + lane]);
                float v2 = __half2float(hs[((size_t)s2 << 6) + lane]);
                float v3 = __half2float(hs[((size_t)s3 << 6) + lane]);
                acc += (v0 + v1) + (v2 + v3);
            }
            for (; k < cnt; ++k)
                acc += __half2float(hs[((size_t)__shfl(cv, k) << 6) + lane]);
        }
        float r = fmaxf(fmaf(acc, dinv[d], bias), 0.f);
        out[((size_t)d << 6) + lane] = __float2half(r);
    }
}

// ---------------- MLP head: out[i] = relu(h@Wh1+bh1) @ Wh2 + bh2 ----------------
__global__ __launch_bounds__(256) void head_kernel(const __half* __restrict__ h,
                                                   const float* __restrict__ Wh1,
                                                   const float* __restrict__ bh1,
                                                   const float* __restrict__ Wh2,
                                                   const float* __restrict__ bh2,
                                                   float* __restrict__ out, int N) {
    __shared__ float Wl[64 * 64];
    for (int i = threadIdx.x; i < 64 * 64; i += blockDim.x) Wl[i] = Wh1[i];
    __syncthreads();
    int lane = threadIdx.x & 63;
    int wavesPerBlock = blockDim.x >> 6;
    int wid = blockIdx.x * wavesPerBlock + (threadIdx.x >> 6);
    int stride = gridDim.x * wavesPerBlock;
    float b = bh1[lane];
    float w2 = Wh2[lane];
    float b2 = bh2[0];
    for (int i = wid; i < N; i += stride) {
        float hv = __half2float(h[((size_t)i << 6) + lane]);
        float acc = b;
#pragma unroll
        for (int k = 0; k < 64; ++k) {
            float xv = __shfl(hv, k);
            acc += xv * Wl[k * 64 + lane];
        }
        acc = fmaxf(acc, 0.f) * w2;
#pragma unroll
        for (int off = 32; off > 0; off >>= 1) acc += __shfl_down(acc, off);
        if (lane == 0) out[i] = acc + b2;
    }
}

extern "C" void kernel_launch(void* const* d_in, const int* in_sizes, int n_in,
                              void* d_out, int out_size, void* d_ws, size_t ws_size,
                              hipStream_t stream) {
    const float* x = (const float*)d_in[0];
    const int* edge = (const int*)d_in[1];   // harness passes integer inputs as int32
    const float* W1 = (const float*)d_in[2];
    const float* b1 = (const float*)d_in[3];
    const float* W2 = (const float*)d_in[4];
    const float* b2 = (const float*)d_in[5];
    const float* W3 = (const float*)d_in[6];
    const float* b3 = (const float*)d_in[7];
    const float* Wh1 = (const float*)d_in[8];
    const float* bh1 = (const float*)d_in[9];
    const float* Wh2 = (const float*)d_in[10];
    const float* bh2 = (const float*)d_in[11];

    int N = in_sizes[0] / 61;   // 100000
    int E = in_sizes[1] / 2;    // 3200000
    const int* srcs = edge;
    const int* dsts = edge + E;
    float* out = (float*)d_out;

    // workspace: dinv(N) | rowptr(N+1) | gcur(FB) | bbase(FB) | col(E) | Ah(N*64 f16) | Bh(N*64 f16)
    // fill staging (srcA 13.65MB + locA 6.83MB = 20.5MB) aliases Ah+Bh (25.6MB, dead until linscale1)
    char* ws = (char*)d_ws;
    size_t off = 0;
    auto alloc = [&](size_t bytes) {
        void* p = ws + off;
        off += (bytes + 255) & ~(size_t)255;
        return p;
    };
    float* dinv = (float*)alloc((size_t)N * 4);
    int* rowptr = (int*)alloc((size_t)(N + 1) * 4);
    int* gcur = (int*)alloc((size_t)FB * 4);
    int* bbase = (int*)alloc((size_t)FB * 4);
    int* col = (int*)alloc((size_t)E * 4);
    __half* Ah = (__half*)alloc((size_t)N * HID * 2);
    __half* Bh = (__half*)alloc((size_t)N * HID * 2);
    if (off > ws_size) return;  // fail cleanly (absmax), not a fault
    int* srcA = (int*)Ah;       // alias: staging dead after fillB (Ah+Bh contiguous = 25.6MB)
    unsigned short* locA = (unsigned short*)((char*)Ah + (size_t)FB * FCAP * 4);

    int gN = (N + 255) / 256;
    int gA = (E + FCH - 1) / FCH;

    // ---- CSR build (once, reused by all 3 layers) ----
    zero_kernel<<<1, 256, 0, stream>>>(gcur, FB);
    fillA_kernel<<<gA, 256, 0, stream>>>(srcs, dsts, gcur, srcA, locA, E);
    bucketscan_kernel<<<1, 256, 0, stream>>>(gcur, bbase, FB);
    fillB_kernel<<<FB, 256, 0, stream>>>(gcur, bbase, srcA, locA, rowptr, dinv, col, N);

    // ---- layer 1 (K=61) ----
    linscale_kernel<61, float><<<gN, 256, 0, stream>>>(x, W1, dinv, Bh, N);
    gather_kernel<<<4096, 256, 0, stream>>>(rowptr, col, dinv, Bh, b1, Ah, N);

    // ---- layer 2 (K=64) ----
    linscale_kernel<64, __half><<<gN, 256, 0, stream>>>(Ah, W2, dinv, Bh, N);
    gather_kernel<<<4096, 256, 0, stream>>>(rowptr, col, dinv, Bh, b2, Ah, N);

    // ---- layer 3 (K=64) ----
    linscale_kernel<64, __half><<<gN, 256, 0, stream>>>(Ah, W3, dinv, Bh, N);
    gather_kernel<<<4096, 256, 0, stream>>>(rowptr, col, dinv, Bh, b3, Ah, N);

    // ---- MLP head ----
    head_kernel<<<1024, 256, 0, stream>>>(Ah, Wh1, bh1, Wh2, bh2, out, N);
}

// Round 12
// 478.432 us; speedup vs baseline: 2.0036x; 1.1253x over previous
//
#include <hip/hip_runtime.h>
#include <hip/hip_fp16.h>

#define HID 64
#define FSH 9                  // nodes per fill bucket = 512
#define FB 196                 // buckets: 196*512 = 100352 >= N
#define FCAP 17408             // per-bucket staging capacity (mean 16326, +8 sigma)
#define FCH 4096               // edges per phase-A block (782 blocks -> ~3/CU)
// packed record: loc(9b) << 17 | src(17b); requires N <= 131072

// ---------------- zero int buffer ----------------
__global__ void zero_kernel(int* __restrict__ p, int n) {
    int i = blockIdx.x * blockDim.x + threadIdx.x;
    if (i < n) p[i] = 0;
}

// ---------------- fill phase A: bin edges into FB dst-buckets (packed staging) ----------------
__global__ __launch_bounds__(256) void fillA_kernel(const int* __restrict__ src,
                                                    const int* __restrict__ dst,
                                                    int* __restrict__ gcur,
                                                    unsigned int* __restrict__ recA,
                                                    int E) {
    __shared__ int hist[FB];
    __shared__ int cur[FB];
    int t = threadIdx.x;
    int base = blockIdx.x * FCH;
    int lim = E - base;
    if (lim > FCH) lim = FCH;
    if (lim <= 0) return;
    for (int i = t; i < FB; i += 256) hist[i] = 0;
    __syncthreads();
    for (int i = t; i < lim; i += 256) atomicAdd(&hist[dst[base + i] >> FSH], 1);
    __syncthreads();
    for (int i = t; i < FB; i += 256) cur[i] = atomicAdd(&gcur[i], hist[i]);
    __syncthreads();
    for (int i = t; i < lim; i += 256) {
        int d = dst[base + i];
        int s = src[base + i];
        int bkt = d >> FSH;
        int idx = atomicAdd(&cur[bkt], 1);
        if (idx < FCAP) {
            recA[(size_t)bkt * FCAP + idx] =
                ((unsigned int)(d & ((1 << FSH) - 1)) << 17) | (unsigned int)s;
        }
    }
}

// ---------------- exclusive scan of FB bucket counts -> bbase ----------------
__global__ __launch_bounds__(256) void bucketscan_kernel(const int* __restrict__ gcur,
                                                         int* __restrict__ bbase, int nb) {
    __shared__ int buf[256];
    int tid = threadIdx.x;
    int v = (tid < nb) ? gcur[tid] : 0;
    buf[tid] = v;
    __syncthreads();
#pragma unroll
    for (int o = 1; o < 256; o <<= 1) {
        int t = (tid >= o) ? buf[tid - o] : 0;
        __syncthreads();
        buf[tid] += t;
        __syncthreads();
    }
    if (tid < nb) bbase[tid] = buf[tid] - v;  // exclusive
}

// ---------------- fill phase B: per-bucket hist + scan + rowptr/dinv + fine fill ----------------
__global__ __launch_bounds__(256) void fillB_kernel(const int* __restrict__ gcur,
                                                    const int* __restrict__ bbase,
                                                    const unsigned int* __restrict__ recA,
                                                    int* __restrict__ rowptr,
                                                    float* __restrict__ dinv,
                                                    int* __restrict__ col, int N) {
    __shared__ int hist[1 << FSH];   // local degree -> later cursor
    __shared__ int buf[256];
    int b = blockIdx.x;
    int t = threadIdx.x;
    int n0 = b << FSH;
    for (int i = t; i < (1 << FSH); i += 256) hist[i] = 0;
    __syncthreads();
    int cnt = gcur[b];
    if (cnt > FCAP) cnt = FCAP;
    const unsigned int* rA = recA + (size_t)b * FCAP;
    for (int r = t; r < cnt; r += 256) atomicAdd(&hist[rA[r] >> 17], 1);
    __syncthreads();
    // scan 512 local degrees (2 per thread)
    int a0 = hist[2 * t], a1 = hist[2 * t + 1];
    int pair = a0 + a1;
    buf[t] = pair;
    __syncthreads();
#pragma unroll
    for (int o = 1; o < 256; o <<= 1) {
        int tv = (t >= o) ? buf[t - o] : 0;
        __syncthreads();
        buf[t] += tv;
        __syncthreads();
    }
    int excl = buf[t] - pair + bbase[b];  // exclusive over pairs + bucket base
    int n_a = n0 + 2 * t, n_b = n0 + 2 * t + 1;
    if (n_a <= N) rowptr[n_a] = excl;
    if (n_b <= N) rowptr[n_b] = excl + a0;
    if (n_a < N) dinv[n_a] = 1.0f / sqrtf((float)(a0 + 1));
    if (n_b < N) dinv[n_b] = 1.0f / sqrtf((float)(a1 + 1));
    __syncthreads();
    hist[2 * t] = excl;            // reuse hist as cursors
    hist[2 * t + 1] = excl + a0;
    __syncthreads();
    for (int r = t; r < cnt; r += 256) {
        unsigned int rec = rA[r];
        int pos = atomicAdd(&hist[rec >> 17], 1);
        col[pos] = (int)(rec & 0x1ffffu);
    }
}

// ---------------- dense linear + dinv scale -> f16 rows: out[n,:] = f16(dinv[n]*(x[n,:]@W)) ----------------
template <int K, typename XT>
__global__ __launch_bounds__(256) void linscale_kernel(const XT* __restrict__ x,
                                                       const float* __restrict__ W,
                                                       const float* __restrict__ dinv,
                                                       __half* __restrict__ out, int N) {
    __shared__ float4 Wl[K * 16];
    const float4* W4 = reinterpret_cast<const float4*>(W);
    for (int i = threadIdx.x; i < K * 16; i += blockDim.x) Wl[i] = W4[i];
    __syncthreads();
    int node = blockIdx.x * blockDim.x + threadIdx.x;
    if (node >= N) return;
    float4 acc[16];
#pragma unroll
    for (int c = 0; c < 16; ++c) acc[c] = make_float4(0.f, 0.f, 0.f, 0.f);
    const XT* xr = x + (size_t)node * K;
    for (int k = 0; k < K; ++k) {
        float xv = (float)xr[k];
#pragma unroll
        for (int c = 0; c < 16; ++c) {
            float4 w = Wl[k * 16 + c];
            acc[c].x += xv * w.x;
            acc[c].y += xv * w.y;
            acc[c].z += xv * w.z;
            acc[c].w += xv * w.w;
        }
    }
    float dv = dinv[node];
    __half2* o = reinterpret_cast<__half2*>(out + (size_t)node * HID);
#pragma unroll
    for (int c = 0; c < 16; ++c) {
        o[c * 2 + 0] = __floats2half2_rn(acc[c].x * dv, acc[c].y * dv);
        o[c * 2 + 1] = __floats2half2_rn(acc[c].z * dv, acc[c].w * dv);
    }
}

// ---------------- gather-aggregate over f16 rows ----------------
// out[d,:] = f16( relu(dinv[d]*(hs[d,:] + sum_e hs[col[e],:]) + b) )
__global__ __launch_bounds__(256) void gather_kernel(const int* __restrict__ rowptr,
                                                     const int* __restrict__ col,
                                                     const float* __restrict__ dinv,
                                                     const __half* __restrict__ hs,
                                                     const float* __restrict__ b,
                                                     __half* __restrict__ out, int N) {
    int lane = threadIdx.x & 63;
    int wid = (blockIdx.x * blockDim.x + threadIdx.x) >> 6;
    int nw = (gridDim.x * blockDim.x) >> 6;
    float bias = b[lane];
    for (int d = wid; d < N; d += nw) {
        int beg = rowptr[d], end = rowptr[d + 1];
        float acc = __half2float(hs[((size_t)d << 6) + lane]);  // self-loop (pre-scaled)
        for (int ebase = beg; ebase < end; ebase += 64) {
            int e = ebase + lane;
            int cv = (e < end) ? col[e] : 0;   // one lane-strided load covers <=64 edges
            int cnt = end - ebase;
            if (cnt > 64) cnt = 64;
            int k = 0;
            for (; k + 4 <= cnt; k += 4) {
                int s0 = __shfl(cv, k + 0);
                int s1 = __shfl(cv, k + 1);
                int s2 = __shfl(cv, k + 2);
                int s3 = __shfl(cv, k + 3);
                float v0 = __half2float(hs[((size_t)s0 << 6) + lane]);
                float v1 = __half2float(hs[((size_t)s1 << 6) + lane]);
                float v2 = __half2float(hs[((size_t)s2 << 6) + lane]);
                float v3 = __half2float(hs[((size_t)s3 << 6) + lane]);
                acc += (v0 + v1) + (v2 + v3);
            }
            for (; k < cnt; ++k)
                acc += __half2float(hs[((size_t)__shfl(cv, k) << 6) + lane]);
        }
        float r = fmaxf(fmaf(acc, dinv[d], bias), 0.f);
        out[((size_t)d << 6) + lane] = __float2half(r);
    }
}

// ---------------- MLP head, thread-per-node: out[i] = relu(h@Wh1+bh1) @ Wh2 + bh2 ----------------
__global__ __launch_bounds__(256) void head_kernel(const __half* __restrict__ h,
                                                   const float* __restrict__ Wh1,
                                                   const float* __restrict__ bh1,
                                                   const float* __restrict__ Wh2,
                                                   const float* __restrict__ bh2,
                                                   float* __restrict__ out, int N) {
    __shared__ float4 Wl[64 * 16];
    __shared__ float bhs[64];
    __shared__ float w2s[64];
    const float4* W4 = reinterpret_cast<const float4*>(Wh1);
    for (int i = threadIdx.x; i < 64 * 16; i += blockDim.x) Wl[i] = W4[i];
    if (threadIdx.x < 64) {
        bhs[threadIdx.x] = bh1[threadIdx.x];
        w2s[threadIdx.x] = Wh2[threadIdx.x];
    }
    __syncthreads();
    int node = blockIdx.x * blockDim.x + threadIdx.x;
    if (node >= N) return;
    float4 acc[16];
#pragma unroll
    for (int c = 0; c < 16; ++c) acc[c] = make_float4(0.f, 0.f, 0.f, 0.f);
    const __half* hr = h + ((size_t)node << 6);
    for (int k = 0; k < 64; ++k) {
        float xv = __half2float(hr[k]);
#pragma unroll
        for (int c = 0; c < 16; ++c) {
            float4 w = Wl[k * 16 + c];
            acc[c].x += xv * w.x;
            acc[c].y += xv * w.y;
            acc[c].z += xv * w.z;
            acc[c].w += xv * w.w;
        }
    }
    float o = 0.f;
#pragma unroll
    for (int c = 0; c < 16; ++c) {
        o += fmaxf(acc[c].x + bhs[4 * c + 0], 0.f) * w2s[4 * c + 0];
        o += fmaxf(acc[c].y + bhs[4 * c + 1], 0.f) * w2s[4 * c + 1];
        o += fmaxf(acc[c].z + bhs[4 * c + 2], 0.f) * w2s[4 * c + 2];
        o += fmaxf(acc[c].w + bhs[4 * c + 3], 0.f) * w2s[4 * c + 3];
    }
    out[node] = o + bh2[0];
}

extern "C" void kernel_launch(void* const* d_in, const int* in_sizes, int n_in,
                              void* d_out, int out_size, void* d_ws, size_t ws_size,
                              hipStream_t stream) {
    const float* x = (const float*)d_in[0];
    const int* edge = (const int*)d_in[1];   // harness passes integer inputs as int32
    const float* W1 = (const float*)d_in[2];
    const float* b1 = (const float*)d_in[3];
    const float* W2 = (const float*)d_in[4];
    const float* b2 = (const float*)d_in[5];
    const float* W3 = (const float*)d_in[6];
    const float* b3 = (const float*)d_in[7];
    const float* Wh1 = (const float*)d_in[8];
    const float* bh1 = (const float*)d_in[9];
    const float* Wh2 = (const float*)d_in[10];
    const float* bh2 = (const float*)d_in[11];

    int N = in_sizes[0] / 61;   // 100000
    int E = in_sizes[1] / 2;    // 3200000
    const int* srcs = edge;
    const int* dsts = edge + E;
    float* out = (float*)d_out;

    // workspace: dinv(N) | rowptr(N+1) | gcur(FB) | bbase(FB) | col(E) | Ah(N*64 f16) | Bh(N*64 f16)
    // fill staging recA (FB*FCAP*4 = 13.65MB) aliases Ah+Bh head (25.6MB, dead until linscale1)
    char* ws = (char*)d_ws;
    size_t off = 0;
    auto alloc = [&](size_t bytes) {
        void* p = ws + off;
        off += (bytes + 255) & ~(size_t)255;
        return p;
    };
    float* dinv = (float*)alloc((size_t)N * 4);
    int* rowptr = (int*)alloc((size_t)(N + 1) * 4);
    int* gcur = (int*)alloc((size_t)FB * 4);
    int* bbase = (int*)alloc((size_t)FB * 4);
    int* col = (int*)alloc((size_t)E * 4);
    __half* Ah = (__half*)alloc((size_t)N * HID * 2);
    __half* Bh = (__half*)alloc((size_t)N * HID * 2);
    if (off > ws_size) return;  // fail cleanly (absmax), not a fault
    unsigned int* recA = (unsigned int*)Ah;  // alias: staging dead after fillB

    int gN = (N + 255) / 256;
    int gA = (E + FCH - 1) / FCH;

    // ---- CSR build (once, reused by all 3 layers) ----
    zero_kernel<<<1, 256, 0, stream>>>(gcur, FB);
    fillA_kernel<<<gA, 256, 0, stream>>>(srcs, dsts, gcur, recA, E);
    bucketscan_kernel<<<1, 256, 0, stream>>>(gcur, bbase, FB);
    fillB_kernel<<<FB, 256, 0, stream>>>(gcur, bbase, recA, rowptr, dinv, col, N);

    // ---- layer 1 (K=61) ----
    linscale_kernel<61, float><<<gN, 256, 0, stream>>>(x, W1, dinv, Bh, N);
    gather_kernel<<<4096, 256, 0, stream>>>(rowptr, col, dinv, Bh, b1, Ah, N);

    // ---- layer 2 (K=64) ----
    linscale_kernel<64, __half><<<gN, 256, 0, stream>>>(Ah, W2, dinv, Bh, N);
    gather_kernel<<<4096, 256, 0, stream>>>(rowptr, col, dinv, Bh, b2, Ah, N);

    // ---- layer 3 (K=64) ----
    linscale_kernel<64, __half><<<gN, 256, 0, stream>>>(Ah, W3, dinv, Bh, N);
    gather_kernel<<<4096, 256, 0, stream>>>(rowptr, col, dinv, Bh, b3, Ah, N);

    // ---- MLP head ----
    head_kernel<<<gN, 256, 0, stream>>>(Ah, Wh1, bh1, Wh2, bh2, out, N);
}

// Round 13
// 442.275 us; speedup vs baseline: 2.1674x; 1.0818x over previous
//
#include <hip/hip_runtime.h>
#include <hip/hip_fp16.h>

#define HID 64
#define FSH 9                  // nodes per fill bucket = 512
#define FB 196                 // buckets: 196*512 = 100352 >= N
#define FCAP 17408             // per-bucket staging capacity (mean 16326, +8 sigma)
#define FCH 4096               // edges per phase-A block (782 blocks -> ~3/CU)
// packed record: loc(9b) << 17 | src(17b); requires N <= 131072

// ---------------- zero int buffer ----------------
__global__ void zero_kernel(int* __restrict__ p, int n) {
    int i = blockIdx.x * blockDim.x + threadIdx.x;
    if (i < n) p[i] = 0;
}

// ---------------- fill phase A: bin edges into FB dst-buckets (packed staging) ----------------
__global__ __launch_bounds__(256) void fillA_kernel(const int* __restrict__ src,
                                                    const int* __restrict__ dst,
                                                    int* __restrict__ gcur,
                                                    unsigned int* __restrict__ recA,
                                                    int E) {
    __shared__ int hist[FB];
    __shared__ int cur[FB];
    int t = threadIdx.x;
    int base = blockIdx.x * FCH;
    int lim = E - base;
    if (lim > FCH) lim = FCH;
    if (lim <= 0) return;
    for (int i = t; i < FB; i += 256) hist[i] = 0;
    __syncthreads();
    for (int i = t; i < lim; i += 256) atomicAdd(&hist[dst[base + i] >> FSH], 1);
    __syncthreads();
    for (int i = t; i < FB; i += 256) cur[i] = atomicAdd(&gcur[i], hist[i]);
    __syncthreads();
    for (int i = t; i < lim; i += 256) {
        int d = dst[base + i];
        int s = src[base + i];
        int bkt = d >> FSH;
        int idx = atomicAdd(&cur[bkt], 1);
        if (idx < FCAP) {
            recA[(size_t)bkt * FCAP + idx] =
                ((unsigned int)(d & ((1 << FSH) - 1)) << 17) | (unsigned int)s;
        }
    }
}

// ---------------- exclusive scan of FB bucket counts -> bbase ----------------
__global__ __launch_bounds__(256) void bucketscan_kernel(const int* __restrict__ gcur,
                                                         int* __restrict__ bbase, int nb) {
    __shared__ int buf[256];
    int tid = threadIdx.x;
    int v = (tid < nb) ? gcur[tid] : 0;
    buf[tid] = v;
    __syncthreads();
#pragma unroll
    for (int o = 1; o < 256; o <<= 1) {
        int t = (tid >= o) ? buf[tid - o] : 0;
        __syncthreads();
        buf[tid] += t;
        __syncthreads();
    }
    if (tid < nb) bbase[tid] = buf[tid] - v;  // exclusive
}

// ---------------- fill phase B: per-bucket hist + scan + rowptr/dinv + fine fill ----------------
__global__ __launch_bounds__(256) void fillB_kernel(const int* __restrict__ gcur,
                                                    const int* __restrict__ bbase,
                                                    const unsigned int* __restrict__ recA,
                                                    int* __restrict__ rowptr,
                                                    float* __restrict__ dinv,
                                                    int* __restrict__ col, int N) {
    __shared__ int hist[1 << FSH];   // local degree -> later cursor
    __shared__ int buf[256];
    int b = blockIdx.x;
    int t = threadIdx.x;
    int n0 = b << FSH;
    for (int i = t; i < (1 << FSH); i += 256) hist[i] = 0;
    __syncthreads();
    int cnt = gcur[b];
    if (cnt > FCAP) cnt = FCAP;
    const unsigned int* rA = recA + (size_t)b * FCAP;
    for (int r = t; r < cnt; r += 256) atomicAdd(&hist[rA[r] >> 17], 1);
    __syncthreads();
    // scan 512 local degrees (2 per thread)
    int a0 = hist[2 * t], a1 = hist[2 * t + 1];
    int pair = a0 + a1;
    buf[t] = pair;
    __syncthreads();
#pragma unroll
    for (int o = 1; o < 256; o <<= 1) {
        int tv = (t >= o) ? buf[t - o] : 0;
        __syncthreads();
        buf[t] += tv;
        __syncthreads();
    }
    int excl = buf[t] - pair + bbase[b];  // exclusive over pairs + bucket base
    int n_a = n0 + 2 * t, n_b = n0 + 2 * t + 1;
    if (n_a <= N) rowptr[n_a] = excl;
    if (n_b <= N) rowptr[n_b] = excl + a0;
    if (n_a < N) dinv[n_a] = 1.0f / sqrtf((float)(a0 + 1));
    if (n_b < N) dinv[n_b] = 1.0f / sqrtf((float)(a1 + 1));
    __syncthreads();
    hist[2 * t] = excl;            // reuse hist as cursors
    hist[2 * t + 1] = excl + a0;
    __syncthreads();
    for (int r = t; r < cnt; r += 256) {
        unsigned int rec = rA[r];
        int pos = atomicAdd(&hist[rec >> 17], 1);
        col[pos] = (int)(rec & 0x1ffffu);
    }
}

// ---------------- dense linear + dinv scale -> f16 rows: out[n,:] = f16(dinv[n]*(x[n,:]@W)) ----------------
template <int K, typename XT>
__global__ __launch_bounds__(256) void linscale_kernel(const XT* __restrict__ x,
                                                       const float* __restrict__ W,
                                                       const float* __restrict__ dinv,
                                                       __half* __restrict__ out, int N) {
    __shared__ float4 Wl[K * 16];
    const float4* W4 = reinterpret_cast<const float4*>(W);
    for (int i = threadIdx.x; i < K * 16; i += blockDim.x) Wl[i] = W4[i];
    __syncthreads();
    int node = blockIdx.x * blockDim.x + threadIdx.x;
    if (node >= N) return;
    float4 acc[16];
#pragma unroll
    for (int c = 0; c < 16; ++c) acc[c] = make_float4(0.f, 0.f, 0.f, 0.f);
    const XT* xr = x + (size_t)node * K;
    for (int k = 0; k < K; ++k) {
        float xv = (float)xr[k];
#pragma unroll
        for (int c = 0; c < 16; ++c) {
            float4 w = Wl[k * 16 + c];
            acc[c].x += xv * w.x;
            acc[c].y += xv * w.y;
            acc[c].z += xv * w.z;
            acc[c].w += xv * w.w;
        }
    }
    float dv = dinv[node];
    __half2* o = reinterpret_cast<__half2*>(out + (size_t)node * HID);
#pragma unroll
    for (int c = 0; c < 16; ++c) {
        o[c * 2 + 0] = __floats2half2_rn(acc[c].x * dv, acc[c].y * dv);
        o[c * 2 + 1] = __floats2half2_rn(acc[c].z * dv, acc[c].w * dv);
    }
}

// ---------------- gather-aggregate: half2 lanes, 2 rows per wave ----------------
// out[d,:] = f16( relu(dinv[d]*(hs[d,:] + sum_e hs[col[e],:]) + b) )
__global__ __launch_bounds__(256) void gather_kernel(const int* __restrict__ rowptr,
                                                     const int* __restrict__ col,
                                                     const float* __restrict__ dinv,
                                                     const __half2* __restrict__ hs2,
                                                     const float* __restrict__ b,
                                                     __half2* __restrict__ out2, int N) {
    int lane = threadIdx.x & 63;
    int hf = lane >> 5;       // which row of the pair
    int gl = lane & 31;       // lane within 32-group = half2 channel pair
    int wid = (blockIdx.x * blockDim.x + threadIdx.x) >> 6;
    int nw = (gridDim.x * blockDim.x) >> 6;
    float bx = b[2 * gl], by = b[2 * gl + 1];
    for (int dbase = wid * 2; dbase < N; dbase += nw * 2) {
        int d = dbase + hf;
        bool act = d < N;
        int dd = act ? d : N - 1;
        int beg = rowptr[dd];
        int end = act ? rowptr[dd + 1] : beg;
        float2 acc = __half22float2(hs2[((size_t)dd << 5) + gl]);  // self-loop
        for (int ebase = beg; ebase < end; ebase += 32) {
            int e = ebase + gl;
            int cv = (e < end) ? col[e] : 0;   // group-strided load: <=32 edges
            int cnt = end - ebase;
            if (cnt > 32) cnt = 32;
            int k = 0;
            for (; k + 4 <= cnt; k += 4) {
                int s0 = __shfl(cv, k + 0, 32);
                int s1 = __shfl(cv, k + 1, 32);
                int s2 = __shfl(cv, k + 2, 32);
                int s3 = __shfl(cv, k + 3, 32);
                float2 v0 = __half22float2(hs2[((size_t)s0 << 5) + gl]);
                float2 v1 = __half22float2(hs2[((size_t)s1 << 5) + gl]);
                float2 v2 = __half22float2(hs2[((size_t)s2 << 5) + gl]);
                float2 v3 = __half22float2(hs2[((size_t)s3 << 5) + gl]);
                acc.x += (v0.x + v1.x) + (v2.x + v3.x);
                acc.y += (v0.y + v1.y) + (v2.y + v3.y);
            }
            for (; k < cnt; ++k) {
                int s = __shfl(cv, k, 32);
                float2 v = __half22float2(hs2[((size_t)s << 5) + gl]);
                acc.x += v.x; acc.y += v.y;
            }
        }
        if (act) {
            float dv = dinv[d];
            float rx = fmaxf(fmaf(acc.x, dv, bx), 0.f);
            float ry = fmaxf(fmaf(acc.y, dv, by), 0.f);
            out2[((size_t)d << 5) + gl] = __floats2half2_rn(rx, ry);
        }
    }
}

// ---------------- MLP head, thread-per-node: out[i] = relu(h@Wh1+bh1) @ Wh2 + bh2 ----------------
__global__ __launch_bounds__(256) void head_kernel(const __half* __restrict__ h,
                                                   const float* __restrict__ Wh1,
                                                   const float* __restrict__ bh1,
                                                   const float* __restrict__ Wh2,
                                                   const float* __restrict__ bh2,
                                                   float* __restrict__ out, int N) {
    __shared__ float4 Wl[64 * 16];
    __shared__ float bhs[64];
    __shared__ float w2s[64];
    const float4* W4 = reinterpret_cast<const float4*>(Wh1);
    for (int i = threadIdx.x; i < 64 * 16; i += blockDim.x) Wl[i] = W4[i];
    if (threadIdx.x < 64) {
        bhs[threadIdx.x] = bh1[threadIdx.x];
        w2s[threadIdx.x] = Wh2[threadIdx.x];
    }
    __syncthreads();
    int node = blockIdx.x * blockDim.x + threadIdx.x;
    if (node >= N) return;
    float4 acc[16];
#pragma unroll
    for (int c = 0; c < 16; ++c) acc[c] = make_float4(0.f, 0.f, 0.f, 0.f);
    const __half* hr = h + ((size_t)node << 6);
    for (int k = 0; k < 64; ++k) {
        float xv = __half2float(hr[k]);
#pragma unroll
        for (int c = 0; c < 16; ++c) {
            float4 w = Wl[k * 16 + c];
            acc[c].x += xv * w.x;
            acc[c].y += xv * w.y;
            acc[c].z += xv * w.z;
            acc[c].w += xv * w.w;
        }
    }
    float o = 0.f;
#pragma unroll
    for (int c = 0; c < 16; ++c) {
        o += fmaxf(acc[c].x + bhs[4 * c + 0], 0.f) * w2s[4 * c + 0];
        o += fmaxf(acc[c].y + bhs[4 * c + 1], 0.f) * w2s[4 * c + 1];
        o += fmaxf(acc[c].z + bhs[4 * c + 2], 0.f) * w2s[4 * c + 2];
        o += fmaxf(acc[c].w + bhs[4 * c + 3], 0.f) * w2s[4 * c + 3];
    }
    out[node] = o + bh2[0];
}

extern "C" void kernel_launch(void* const* d_in, const int* in_sizes, int n_in,
                              void* d_out, int out_size, void* d_ws, size_t ws_size,
                              hipStream_t stream) {
    const float* x = (const float*)d_in[0];
    const int* edge = (const int*)d_in[1];   // harness passes integer inputs as int32
    const float* W1 = (const float*)d_in[2];
    const float* b1 = (const float*)d_in[3];
    const float* W2 = (const float*)d_in[4];
    const float* b2 = (const float*)d_in[5];
    const float* W3 = (const float*)d_in[6];
    const float* b3 = (const float*)d_in[7];
    const float* Wh1 = (const float*)d_in[8];
    const float* bh1 = (const float*)d_in[9];
    const float* Wh2 = (const float*)d_in[10];
    const float* bh2 = (const float*)d_in[11];

    int N = in_sizes[0] / 61;   // 100000
    int E = in_sizes[1] / 2;    // 3200000
    const int* srcs = edge;
    const int* dsts = edge + E;
    float* out = (float*)d_out;

    // workspace: dinv(N) | rowptr(N+1) | gcur(FB) | bbase(FB) | col(E) | Ah(N*64 f16) | Bh(N*64 f16)
    // fill staging recA (FB*FCAP*4 = 13.65MB) aliases Ah+Bh head (25.6MB, dead until linscale1)
    char* ws = (char*)d_ws;
    size_t off = 0;
    auto alloc = [&](size_t bytes) {
        void* p = ws + off;
        off += (bytes + 255) & ~(size_t)255;
        return p;
    };
    float* dinv = (float*)alloc((size_t)N * 4);
    int* rowptr = (int*)alloc((size_t)(N + 1) * 4);
    int* gcur = (int*)alloc((size_t)FB * 4);
    int* bbase = (int*)alloc((size_t)FB * 4);
    int* col = (int*)alloc((size_t)E * 4);
    __half* Ah = (__half*)alloc((size_t)N * HID * 2);
    __half* Bh = (__half*)alloc((size_t)N * HID * 2);
    if (off > ws_size) return;  // fail cleanly (absmax), not a fault
    unsigned int* recA = (unsigned int*)Ah;  // alias: staging dead after fillB

    int gN = (N + 255) / 256;
    int gA = (E + FCH - 1) / FCH;

    // ---- CSR build (once, reused by all 3 layers) ----
    zero_kernel<<<1, 256, 0, stream>>>(gcur, FB);
    fillA_kernel<<<gA, 256, 0, stream>>>(srcs, dsts, gcur, recA, E);
    bucketscan_kernel<<<1, 256, 0, stream>>>(gcur, bbase, FB);
    fillB_kernel<<<FB, 256, 0, stream>>>(gcur, bbase, recA, rowptr, dinv, col, N);

    // ---- layer 1 (K=61) ----
    linscale_kernel<61, float><<<gN, 256, 0, stream>>>(x, W1, dinv, Bh, N);
    gather_kernel<<<4096, 256, 0, stream>>>(rowptr, col, dinv,
                                            (const __half2*)Bh, b1, (__half2*)Ah, N);

    // ---- layer 2 (K=64) ----
    linscale_kernel<64, __half><<<gN, 256, 0, stream>>>(Ah, W2, dinv, Bh, N);
    gather_kernel<<<4096, 256, 0, stream>>>(rowptr, col, dinv,
                                            (const __half2*)Bh, b2, (__half2*)Ah, N);

    // ---- layer 3 (K=64) ----
    linscale_kernel<64, __half><<<gN, 256, 0, stream>>>(Ah, W3, dinv, Bh, N);
    gather_kernel<<<4096, 256, 0, stream>>>(rowptr, col, dinv,
                                            (const __half2*)Bh, b3, (__half2*)Ah, N);

    // ---- MLP head ----
    head_kernel<<<gN, 256, 0, stream>>>(Ah, Wh1, bh1, Wh2, bh2, out, N);
}